// Round 13
// baseline (814.233 us; speedup 1.0000x reference)
//
#include <hip/hip_runtime.h>

typedef __attribute__((ext_vector_type(8))) __bf16 bf16x8;
typedef __attribute__((ext_vector_type(4))) float f32x4;

#define GLOAD_LDS16(g, l)                                                     \
  __builtin_amdgcn_global_load_lds(                                           \
      (const __attribute__((address_space(1))) void*)(g),                     \
      (__attribute__((address_space(3))) void*)(l), 16, 0, 0)

#define BAR() __builtin_amdgcn_s_barrier()
#define SB0() __builtin_amdgcn_sched_barrier(0)
#define LGKM(n)                                                               \
  do {                                                                        \
    asm volatile("s_waitcnt lgkmcnt(" #n ")" ::: "memory");                   \
    SB0();                                                                    \
  } while (0)
#define VMCNT0() asm volatile("s_waitcnt vmcnt(0)" ::: "memory")
#define PRIO1() __builtin_amdgcn_s_setprio(1)
#define PRIO0() __builtin_amdgcn_s_setprio(0)
#define MFMA_BF16 __builtin_amdgcn_mfma_f32_16x16x32_bf16

__device__ __forceinline__ unsigned short f32_to_bf16(float f) {
  unsigned int u = __builtin_bit_cast(unsigned int, f);
  u += 0x7FFFu + ((u >> 16) & 1u);
  return (unsigned short)(u >> 16);
}

// ---------- merged f32 -> bf16 conversion for x, W1, W3 (one launch) -------
__global__ void conv3_f32_bf16(const float* __restrict__ s0,
                               unsigned short* __restrict__ d0,
                               const float* __restrict__ s1,
                               unsigned short* __restrict__ d1,
                               const float* __restrict__ s2,
                               unsigned short* __restrict__ d2, int n4) {
  const int seg = blockIdx.x >> 10;  // 1024 blocks per segment
  const int b = blockIdx.x & 1023;
  const float* in = (seg == 0) ? s0 : (seg == 1) ? s1 : s2;
  unsigned short* out = (seg == 0) ? d0 : (seg == 1) ? d1 : d2;
  const int stride = 1024 * blockDim.x;
  for (int i = b * blockDim.x + threadIdx.x; i < n4; i += stride) {
    float4 v = reinterpret_cast<const float4*>(in)[i];
    ushort4 o;
    o.x = f32_to_bf16(v.x);
    o.y = f32_to_bf16(v.y);
    o.z = f32_to_bf16(v.z);
    o.w = f32_to_bf16(v.w);
    reinterpret_cast<ushort4*>(out)[i] = o;
  }
}

// ---------------- FWHT rows of 8192, * 1/sqrt(8192), bf16 out --------------
__global__ void fwht_rows_bf16(const float* __restrict__ in,
                               unsigned short* __restrict__ out) {
  __shared__ float s[8192];
  const int tid = threadIdx.x;  // 256 threads
  const float* row = in + (size_t)blockIdx.x * 8192;
#pragma unroll
  for (int i = 0; i < 8; ++i)
    reinterpret_cast<float4*>(s)[tid + i * 256] =
        reinterpret_cast<const float4*>(row)[tid + i * 256];
  for (int h = 1; h < 8192; h <<= 1) {
    __syncthreads();
#pragma unroll
    for (int it = 0; it < 16; ++it) {
      int i = tid + it * 256;
      int j = ((i & ~(h - 1)) << 1) | (i & (h - 1));
      float a = s[j], b = s[j + h];
      s[j] = a + b;
      s[j + h] = a - b;
    }
  }
  __syncthreads();
  const float scale = 0.011048543456039806f;  // 1/sqrt(8192)
  unsigned short* orow = out + (size_t)blockIdx.x * 8192;
#pragma unroll
  for (int i = 0; i < 8; ++i) {
    float4 v = reinterpret_cast<const float4*>(s)[tid + i * 256];
    ushort4 o;
    o.x = f32_to_bf16(v.x * scale);
    o.y = f32_to_bf16(v.y * scale);
    o.z = f32_to_bf16(v.z * scale);
    o.w = f32_to_bf16(v.w * scale);
    reinterpret_cast<ushort4*>(orow)[tid + i * 256] = o;
  }
}

// ======================= GEMM2: C(f32) = A · Bt^T ==========================
// tile 256x256, BK=64, 8 waves (2M x 4N), per-wave 128x64. R12 structure;
// odd waves run the mirrored quadrant order (A-hi first) to antiphase the
// LDS-read bursts against even waves' MFMA clusters. Same registers, same
// barrier count, same gate arithmetic.
#define G2_STAGE(bi, tt)                                                      \
  if ((tt) + 1 < NT) {                                                        \
    unsigned short* dA = L + (((bi) ^ 1) * 16384) + wid * 512;                \
    unsigned short* dB = L + 32768 + (((bi) ^ 1) * 16384) + wid * 512;        \
    _Pragma("unroll") for (int i = 0; i < 4; ++i) {                           \
      GLOAD_LDS16(pA + i * s64, dA + i * 4096);                               \
      GLOAD_LDS16(pB + i * s64, dB + i * 4096);                               \
    }                                                                         \
  }                                                                           \
  SB0();

#define G2_RA(mi, bi)                                                         \
  {                                                                           \
    ra[(mi)&3][0] = *(const bf16x8*)(Lb + ((bi)*32768 + (mi)*2048) + rA0);    \
    ra[(mi)&3][1] = *(const bf16x8*)(Lb + ((bi)*32768 + (mi)*2048) + rA1);    \
  }
#define G2_RB(ni, bi)                                                         \
  {                                                                           \
    rb[ni][0] = *(const bf16x8*)(Lb + ((bi)*32768 + (ni)*2048) + rB0);        \
    rb[ni][1] = *(const bf16x8*)(Lb + ((bi)*32768 + (ni)*2048) + rB1);        \
  }
#define G2_MM(ao, no, nhi)                                                    \
  _Pragma("unroll") for (int m = 0; m < 4; ++m)                               \
      _Pragma("unroll") for (int n = (no); n < (nhi); ++n) {                  \
    acc[(ao) + m][n] = MFMA_BF16(ra[m][0], rb[n][0], acc[(ao) + m][n], 0, 0,  \
                                 0);                                          \
    acc[(ao) + m][n] = MFMA_BF16(ra[m][1], rb[n][1], acc[(ao) + m][n], 0, 0,  \
                                 0);                                          \
  }

#define G2_TILE_P(bi, tt, AOF, AOS)                                           \
  {                                                                           \
    G2_STAGE(bi, tt)                                                          \
    G2_RA((AOF) + 0, bi) G2_RA((AOF) + 1, bi)                                 \
    G2_RA((AOF) + 2, bi) G2_RA((AOF) + 3, bi)                                 \
    G2_RB(0, bi) G2_RB(1, bi)                                                 \
    SB0();                                                                    \
    G2_RB(2, bi) G2_RB(3, bi)                                                 \
    SB0();                                                                    \
    LGKM(4);                                                                  \
    PRIO1();                                                                  \
    G2_MM(AOF, 0, 2)                                                          \
    PRIO0();                                                                  \
    SB0();                                                                    \
    LGKM(0);                                                                  \
    PRIO1();                                                                  \
    G2_MM(AOF, 2, 4)                                                          \
    PRIO0();                                                                  \
    SB0();                                                                    \
    G2_RA((AOS) + 0, bi) G2_RA((AOS) + 1, bi)                                 \
    G2_RA((AOS) + 2, bi) G2_RA((AOS) + 3, bi)                                 \
    SB0();                                                                    \
    LGKM(0);                                                                  \
    PRIO1();                                                                  \
    G2_MM(AOS, 2, 4)                                                          \
    G2_MM(AOS, 0, 2)                                                          \
    PRIO0();                                                                  \
    VMCNT0();                                                                 \
    BAR();                                                                    \
    pA += 128;                                                                \
    pB += 128;                                                                \
  }

__launch_bounds__(512, 2)
__global__ void gemm2_pipe(const unsigned short* __restrict__ A,
                           const unsigned short* __restrict__ Bt,
                           float* __restrict__ C, int M, int N, int K) {
  __shared__ __align__(16) unsigned short L[65536];  // A:[0,64KB) B:[64,128KB)
  const int tid = threadIdx.x, lane = tid & 63, wid = tid >> 6;
  const int wr = wid >> 2, wc = wid & 3;
  const int nbx = N >> 8;
  const int cpx = (int)gridDim.x >> 3;
  const int swz = ((int)blockIdx.x & 7) * cpx + ((int)blockIdx.x >> 3);
  const int bm = (swz / nbx) << 8, bn = (swz % nbx) << 8;
  const int NT = K >> 6;

  const int lp0 = (lane & 15) * 128 + (((lane >> 4) << 4) ^ ((lane & 7) << 4));
  const int lp1 =
      (lane & 15) * 128 + ((64 | ((lane >> 4) << 4)) ^ ((lane & 7) << 4));
  const int rA0 = wr * 16384 + lp0, rA1 = wr * 16384 + lp1;
  const int rB0 = 65536 + wc * 8192 + lp0, rB1 = 65536 + wc * 8192 + lp1;

  const int swzc = ((lane & 7) ^ (lane >> 3)) << 4;
  const char* pA = (const char*)A +
                   ((size_t)(bm + (wid << 3) + (lane >> 3)) * K) * 2 + swzc;
  const char* pB = (const char*)Bt +
                   ((size_t)(bn + (wid << 3) + (lane >> 3)) * K) * 2 + swzc;
  const size_t s64 = (size_t)K * 128;
  const char* Lb = (const char*)L;

  {  // prologue: stage tile 0 into buf0
    unsigned short* dA = L + wid * 512;
    unsigned short* dB = L + 32768 + wid * 512;
#pragma unroll
    for (int i = 0; i < 4; ++i) {
      GLOAD_LDS16(pA + i * s64, dA + i * 4096);
      GLOAD_LDS16(pB + i * s64, dB + i * 4096);
    }
  }
  pA += 128;
  pB += 128;

  f32x4 acc[8][4];
#pragma unroll
  for (int m = 0; m < 8; ++m)
#pragma unroll
    for (int n = 0; n < 4; ++n) acc[m][n] = (f32x4)0.0f;
  bf16x8 ra[4][2], rb[4][2];

  VMCNT0();
  BAR();

  if ((wid & 1) == 0) {
    for (int t = 0; t < NT; t += 2) {
      G2_TILE_P(0, t, 0, 4)
      G2_TILE_P(1, t + 1, 0, 4)
    }
  } else {  // mirrored: A-hi quadrants first
    for (int t = 0; t < NT; t += 2) {
      G2_TILE_P(0, t, 4, 0)
      G2_TILE_P(1, t + 1, 4, 0)
    }
  }

  const int er = (lane >> 4) << 2;
  const int ec = lane & 15;
#pragma unroll
  for (int mi = 0; mi < 8; ++mi)
#pragma unroll
    for (int n = 0; n < 4; ++n)
#pragma unroll
      for (int r = 0; r < 4; ++r) {
        size_t row = (size_t)(bm + wr * 128 + mi * 16 + er + r);
        size_t col = (size_t)(bn + wc * 64 + n * 16 + ec);
        C[row * N + col] = acc[mi][n][r];
      }
}

// ======================= GEMM1: dual-B + silu fuse =========================
// tile 256x128, BK=64, 8 waves (4M x 2N), per-wave 64x64, dual accum.
// LDS (ushorts): A [0,32768), B1 [32768,49152), B3 [49152,65536).
// Odd waves: B3/L quadrants first, then B1/G (mirrored order, same regs).
#define G1_STAGE(bi, tt)                                                      \
  if ((tt) + 1 < NT) {                                                        \
    unsigned short* dA = L + (((bi) ^ 1) * 16384) + wid * 512;                \
    unsigned short* dB1 = L + 32768 + (((bi) ^ 1) * 8192) + wid * 512;        \
    unsigned short* dB3 = L + 49152 + (((bi) ^ 1) * 8192) + wid * 512;        \
    _Pragma("unroll") for (int i = 0; i < 4; ++i)                             \
        GLOAD_LDS16(pA + i * s64, dA + i * 4096);                             \
    _Pragma("unroll") for (int i = 0; i < 2; ++i) {                           \
      GLOAD_LDS16(pB1 + i * s64, dB1 + i * 4096);                             \
      GLOAD_LDS16(pB3 + i * s64, dB3 + i * 4096);                             \
    }                                                                         \
  }                                                                           \
  SB0();

#define G1_RA(mi, bi)                                                         \
  {                                                                           \
    ra[mi][0] = *(const bf16x8*)(Lb + ((bi)*32768 + (mi)*2048) + rA0);        \
    ra[mi][1] = *(const bf16x8*)(Lb + ((bi)*32768 + (mi)*2048) + rA1);        \
  }
#define G1_RB(ni, base, bi)                                                   \
  {                                                                           \
    rb[ni][0] =                                                               \
        *(const bf16x8*)(Lb + ((base) + (bi)*16384 + (ni)*2048) + rB0);       \
    rb[ni][1] =                                                               \
        *(const bf16x8*)(Lb + ((base) + (bi)*16384 + (ni)*2048) + rB1);       \
  }
#define G1_MM(ACC, no, nhi)                                                   \
  _Pragma("unroll") for (int m = 0; m < 4; ++m)                               \
      _Pragma("unroll") for (int n = (no); n < (nhi); ++n) {                  \
    ACC[m][n] = MFMA_BF16(ra[m][0], rb[n][0], ACC[m][n], 0, 0, 0);            \
    ACC[m][n] = MFMA_BF16(ra[m][1], rb[n][1], ACC[m][n], 0, 0, 0);            \
  }

// Even: B1(G) n01,n23 then B3(L) n23,n01.  Odd: B3(L) n23,n01 then B1(G).
#define G1_TILE_E(bi, tt)                                                     \
  {                                                                           \
    G1_STAGE(bi, tt)                                                          \
    G1_RA(0, bi) G1_RA(1, bi) G1_RA(2, bi) G1_RA(3, bi)                       \
    G1_RB(0, 65536, bi) G1_RB(1, 65536, bi)                                   \
    SB0();                                                                    \
    G1_RB(2, 65536, bi) G1_RB(3, 65536, bi)                                   \
    SB0();                                                                    \
    LGKM(4);                                                                  \
    PRIO1(); G1_MM(accG, 0, 2) PRIO0();                                       \
    SB0();                                                                    \
    LGKM(0);                                                                  \
    PRIO1(); G1_MM(accG, 2, 4) PRIO0();                                       \
    SB0();                                                                    \
    G1_RB(2, 98304, bi) G1_RB(3, 98304, bi)                                   \
    SB0();                                                                    \
    G1_RB(0, 98304, bi) G1_RB(1, 98304, bi)                                   \
    SB0();                                                                    \
    LGKM(4);                                                                  \
    PRIO1(); G1_MM(accL, 2, 4) PRIO0();                                       \
    SB0();                                                                    \
    LGKM(0);                                                                  \
    PRIO1(); G1_MM(accL, 0, 2) PRIO0();                                       \
    VMCNT0();                                                                 \
    BAR();                                                                    \
    pA += 128;                                                                \
    pB1 += 128;                                                               \
    pB3 += 128;                                                               \
  }

#define G1_TILE_O(bi, tt)                                                     \
  {                                                                           \
    G1_STAGE(bi, tt)                                                          \
    G1_RA(0, bi) G1_RA(1, bi) G1_RA(2, bi) G1_RA(3, bi)                       \
    G1_RB(2, 98304, bi) G1_RB(3, 98304, bi)                                   \
    SB0();                                                                    \
    G1_RB(0, 98304, bi) G1_RB(1, 98304, bi)                                   \
    SB0();                                                                    \
    LGKM(4);                                                                  \
    PRIO1(); G1_MM(accL, 2, 4) PRIO0();                                       \
    SB0();                                                                    \
    LGKM(0);                                                                  \
    PRIO1(); G1_MM(accL, 0, 2) PRIO0();                                       \
    SB0();                                                                    \
    G1_RB(0, 65536, bi) G1_RB(1, 65536, bi)                                   \
    SB0();                                                                    \
    G1_RB(2, 65536, bi) G1_RB(3, 65536, bi)                                   \
    SB0();                                                                    \
    LGKM(4);                                                                  \
    PRIO1(); G1_MM(accG, 0, 2) PRIO0();                                       \
    SB0();                                                                    \
    LGKM(0);                                                                  \
    PRIO1(); G1_MM(accG, 2, 4) PRIO0();                                       \
    VMCNT0();                                                                 \
    BAR();                                                                    \
    pA += 128;                                                                \
    pB1 += 128;                                                               \
    pB3 += 128;                                                               \
  }

__launch_bounds__(512, 2)
__global__ void gemm1_pipe(const unsigned short* __restrict__ A,
                           const unsigned short* __restrict__ B1p,
                           const unsigned short* __restrict__ B3p,
                           unsigned short* __restrict__ Hout, int M, int N,
                           int K) {
  __shared__ __align__(16) unsigned short L[65536];
  const int tid = threadIdx.x, lane = tid & 63, wid = tid >> 6;
  const int wr = wid >> 1, wc = wid & 1;
  const int nby = M >> 8;  // 32
  const int cpx = (int)gridDim.x >> 3;
  const int swz = ((int)blockIdx.x & 7) * cpx + ((int)blockIdx.x >> 3);
  const int bm = (swz % nby) << 8;
  const int bn = (swz / nby) << 7;
  const int NT = K >> 6;

  const int lp0 = (lane & 15) * 128 + (((lane >> 4) << 4) ^ ((lane & 7) << 4));
  const int lp1 =
      (lane & 15) * 128 + ((64 | ((lane >> 4) << 4)) ^ ((lane & 7) << 4));
  const int rA0 = wr * 8192 + lp0, rA1 = wr * 8192 + lp1;
  const int rB0 = wc * 8192 + lp0, rB1 = wc * 8192 + lp1;

  const int swzc = ((lane & 7) ^ (lane >> 3)) << 4;
  const char* pA = (const char*)A +
                   ((size_t)(bm + (wid << 3) + (lane >> 3)) * K) * 2 + swzc;
  const char* pB1 = (const char*)B1p +
                    ((size_t)(bn + (wid << 3) + (lane >> 3)) * K) * 2 + swzc;
  const char* pB3 = (const char*)B3p +
                    ((size_t)(bn + (wid << 3) + (lane >> 3)) * K) * 2 + swzc;
  const size_t s64 = (size_t)K * 128;
  const char* Lb = (const char*)L;

  {  // prologue
    unsigned short* dA = L + wid * 512;
    unsigned short* dB1 = L + 32768 + wid * 512;
    unsigned short* dB3 = L + 49152 + wid * 512;
#pragma unroll
    for (int i = 0; i < 4; ++i) GLOAD_LDS16(pA + i * s64, dA + i * 4096);
#pragma unroll
    for (int i = 0; i < 2; ++i) {
      GLOAD_LDS16(pB1 + i * s64, dB1 + i * 4096);
      GLOAD_LDS16(pB3 + i * s64, dB3 + i * 4096);
    }
  }
  pA += 128;
  pB1 += 128;
  pB3 += 128;

  f32x4 accG[4][4], accL[4][4];
#pragma unroll
  for (int m = 0; m < 4; ++m)
#pragma unroll
    for (int n = 0; n < 4; ++n) {
      accG[m][n] = (f32x4)0.0f;
      accL[m][n] = (f32x4)0.0f;
    }
  bf16x8 ra[4][2], rb[4][2];

  VMCNT0();
  BAR();

  if ((wid & 1) == 0) {
    for (int t = 0; t < NT; t += 2) {
      G1_TILE_E(0, t)
      G1_TILE_E(1, t + 1)
    }
  } else {
    for (int t = 0; t < NT; t += 2) {
      G1_TILE_O(0, t)
      G1_TILE_O(1, t + 1)
    }
  }

  const int er = (lane >> 4) << 2;
  const int ec = lane & 15;
#pragma unroll
  for (int m = 0; m < 4; ++m)
#pragma unroll
    for (int n = 0; n < 4; ++n)
#pragma unroll
      for (int r = 0; r < 4; ++r) {
        float g = accG[m][n][r];
        float li = accL[m][n][r];
        float h = (g / (1.0f + __expf(-g))) * li;
        size_t row = (size_t)(bm + wr * 64 + m * 16 + er + r);
        size_t col = (size_t)(bn + wc * 64 + n * 16 + ec);
        Hout[row * N + col] = f32_to_bf16(h);
      }
}

extern "C" void kernel_launch(void* const* d_in, const int* in_sizes, int n_in,
                              void* d_out, int out_size, void* d_ws,
                              size_t ws_size, hipStream_t stream) {
  const float* x = (const float*)d_in[0];   // (4,2048,2048)
  const float* W1 = (const float*)d_in[1];  // (8192,2048)
  const float* W2 = (const float*)d_in[2];  // (2048,8192)
  const float* W3 = (const float*)d_in[3];  // (8192,2048)
  float* out = (float*)d_out;

  const int M = 8192, D = 2048, H = 8192;
  const size_t NE = (size_t)16777216;

  unsigned short* xb = (unsigned short*)d_ws;
  unsigned short* w1b = xb + NE;
  unsigned short* w3b = w1b + NE;
  unsigned short* w2f = w3b + NE;
  unsigned short* hid = w2f + NE;  // M x H bf16

  conv3_f32_bf16<<<3072, 256, 0, stream>>>(x, xb, W1, w1b, W3, w3b,
                                           (int)(NE / 4));
  fwht_rows_bf16<<<2048, 256, 0, stream>>>(W2, w2f);

  gemm1_pipe<<<(M / 256) * (H / 128), 512, 0, stream>>>(xb, w1b, w3b, hid, M,
                                                        H, D);
  gemm2_pipe<<<(M / 256) * (D / 256), 512, 0, stream>>>(hid, w2f, out, M, D,
                                                        H);
}

// Round 14
// 809.261 us; speedup vs baseline: 1.0061x; 1.0061x over previous
//
#include <hip/hip_runtime.h>

typedef __attribute__((ext_vector_type(8))) __bf16 bf16x8;
typedef __attribute__((ext_vector_type(4))) float f32x4;

#define GLOAD_LDS16(g, l)                                                     \
  __builtin_amdgcn_global_load_lds(                                           \
      (const __attribute__((address_space(1))) void*)(g),                     \
      (__attribute__((address_space(3))) void*)(l), 16, 0, 0)

#define BAR() __builtin_amdgcn_s_barrier()
#define SB0() __builtin_amdgcn_sched_barrier(0)
#define LGKM0()                                                               \
  do {                                                                        \
    asm volatile("s_waitcnt lgkmcnt(0)" ::: "memory");                        \
    SB0();                                                                    \
  } while (0)
#define VMCNT0() asm volatile("s_waitcnt vmcnt(0)" ::: "memory")
#define MFMA_BF16 __builtin_amdgcn_mfma_f32_16x16x32_bf16

__device__ __forceinline__ unsigned short f32_to_bf16(float f) {
  unsigned int u = __builtin_bit_cast(unsigned int, f);
  u += 0x7FFFu + ((u >> 16) & 1u);
  return (unsigned short)(u >> 16);
}

// ---------- merged f32 -> bf16 conversion for x, W1, W3 (one launch) -------
__global__ void conv3_f32_bf16(const float* __restrict__ s0,
                               unsigned short* __restrict__ d0,
                               const float* __restrict__ s1,
                               unsigned short* __restrict__ d1,
                               const float* __restrict__ s2,
                               unsigned short* __restrict__ d2, int n4) {
  const int seg = blockIdx.x >> 10;  // 1024 blocks per segment
  const int b = blockIdx.x & 1023;
  const float* in = (seg == 0) ? s0 : (seg == 1) ? s1 : s2;
  unsigned short* out = (seg == 0) ? d0 : (seg == 1) ? d1 : d2;
  const int stride = 1024 * blockDim.x;
  for (int i = b * blockDim.x + threadIdx.x; i < n4; i += stride) {
    float4 v = reinterpret_cast<const float4*>(in)[i];
    ushort4 o;
    o.x = f32_to_bf16(v.x);
    o.y = f32_to_bf16(v.y);
    o.z = f32_to_bf16(v.z);
    o.w = f32_to_bf16(v.w);
    reinterpret_cast<ushort4*>(out)[i] = o;
  }
}

// ---------------- FWHT rows of 8192, * 1/sqrt(8192), bf16 out --------------
__global__ void fwht_rows_bf16(const float* __restrict__ in,
                               unsigned short* __restrict__ out) {
  __shared__ float s[8192];
  const int tid = threadIdx.x;  // 256 threads
  const float* row = in + (size_t)blockIdx.x * 8192;
#pragma unroll
  for (int i = 0; i < 8; ++i)
    reinterpret_cast<float4*>(s)[tid + i * 256] =
        reinterpret_cast<const float4*>(row)[tid + i * 256];
  for (int h = 1; h < 8192; h <<= 1) {
    __syncthreads();
#pragma unroll
    for (int it = 0; it < 16; ++it) {
      int i = tid + it * 256;
      int j = ((i & ~(h - 1)) << 1) | (i & (h - 1));
      float a = s[j], b = s[j + h];
      s[j] = a + b;
      s[j + h] = a - b;
    }
  }
  __syncthreads();
  const float scale = 0.011048543456039806f;  // 1/sqrt(8192)
  unsigned short* orow = out + (size_t)blockIdx.x * 8192;
#pragma unroll
  for (int i = 0; i < 8; ++i) {
    float4 v = reinterpret_cast<const float4*>(s)[tid + i * 256];
    ushort4 o;
    o.x = f32_to_bf16(v.x * scale);
    o.y = f32_to_bf16(v.y * scale);
    o.z = f32_to_bf16(v.z * scale);
    o.w = f32_to_bf16(v.w * scale);
    reinterpret_cast<ushort4*>(orow)[tid + i * 256] = o;
  }
}

// ======================= GEMM2: C(f32) = A · Bt^T ==========================
// tile 256x256, BK=64, 8 waves (2M x 4N), per-wave 128x64.
// Compiler-free tile body: stage pinned at head (SB0), then all 24 ds_reads
// + 32 MFMAs with NO manual gates -- compiler emits fine-grained lgkmcnt.
// Tile closes with lgkm(0) (reads must retire before barrier: raw s_barrier
// does not drain lgkm and buf[bi] is re-staged next tile) + vmcnt(0) + BAR.
#define G2_TILE(bi, tt)                                                       \
  {                                                                           \
    if ((tt) + 1 < NT) {                                                      \
      unsigned short* dA = L + (((bi) ^ 1) * 16384) + wid * 512;              \
      unsigned short* dB = L + 32768 + (((bi) ^ 1) * 16384) + wid * 512;      \
      _Pragma("unroll") for (int i = 0; i < 4; ++i) {                         \
        GLOAD_LDS16(pA + i * s64, dA + i * 4096);                             \
        GLOAD_LDS16(pB + i * s64, dB + i * 4096);                             \
      }                                                                       \
    }                                                                         \
    SB0();                                                                    \
    _Pragma("unroll") for (int m = 0; m < 8; ++m) {                           \
      ra[m][0] = *(const bf16x8*)(Lb + ((bi)*32768 + m * 2048) + rA0);        \
      ra[m][1] = *(const bf16x8*)(Lb + ((bi)*32768 + m * 2048) + rA1);        \
    }                                                                         \
    _Pragma("unroll") for (int n = 0; n < 4; ++n) {                           \
      rb[n][0] = *(const bf16x8*)(Lb + ((bi)*32768 + n * 2048) + rB0);        \
      rb[n][1] = *(const bf16x8*)(Lb + ((bi)*32768 + n * 2048) + rB1);        \
    }                                                                         \
    _Pragma("unroll") for (int m = 0; m < 8; ++m)                             \
        _Pragma("unroll") for (int n = 0; n < 4; ++n)                         \
            _Pragma("unroll") for (int ks = 0; ks < 2; ++ks) acc[m][n] =      \
                MFMA_BF16(ra[m][ks], rb[n][ks], acc[m][n], 0, 0, 0);          \
    LGKM0();                                                                  \
    VMCNT0();                                                                 \
    BAR();                                                                    \
    pA += 128;                                                                \
    pB += 128;                                                                \
  }

__launch_bounds__(512, 2)
__global__ void gemm2_pipe(const unsigned short* __restrict__ A,
                           const unsigned short* __restrict__ Bt,
                           float* __restrict__ C, int M, int N, int K) {
  __shared__ __align__(16) unsigned short L[65536];  // A:[0,64KB) B:[64,128KB)
  const int tid = threadIdx.x, lane = tid & 63, wid = tid >> 6;
  const int wr = wid >> 2, wc = wid & 3;
  const int nbx = N >> 8;
  const int cpx = (int)gridDim.x >> 3;
  const int swz = ((int)blockIdx.x & 7) * cpx + ((int)blockIdx.x >> 3);
  const int bm = (swz / nbx) << 8, bn = (swz % nbx) << 8;
  const int NT = K >> 6;

  const int lp0 = (lane & 15) * 128 + (((lane >> 4) << 4) ^ ((lane & 7) << 4));
  const int lp1 =
      (lane & 15) * 128 + ((64 | ((lane >> 4) << 4)) ^ ((lane & 7) << 4));
  const int rA0 = wr * 16384 + lp0, rA1 = wr * 16384 + lp1;
  const int rB0 = 65536 + wc * 8192 + lp0, rB1 = 65536 + wc * 8192 + lp1;

  const int swzc = ((lane & 7) ^ (lane >> 3)) << 4;
  const char* pA = (const char*)A +
                   ((size_t)(bm + (wid << 3) + (lane >> 3)) * K) * 2 + swzc;
  const char* pB = (const char*)Bt +
                   ((size_t)(bn + (wid << 3) + (lane >> 3)) * K) * 2 + swzc;
  const size_t s64 = (size_t)K * 128;
  const char* Lb = (const char*)L;

  {  // prologue: stage tile 0 into buf0
    unsigned short* dA = L + wid * 512;
    unsigned short* dB = L + 32768 + wid * 512;
#pragma unroll
    for (int i = 0; i < 4; ++i) {
      GLOAD_LDS16(pA + i * s64, dA + i * 4096);
      GLOAD_LDS16(pB + i * s64, dB + i * 4096);
    }
  }
  pA += 128;
  pB += 128;

  f32x4 acc[8][4];
#pragma unroll
  for (int m = 0; m < 8; ++m)
#pragma unroll
    for (int n = 0; n < 4; ++n) acc[m][n] = (f32x4)0.0f;
  bf16x8 ra[8][2], rb[4][2];

  VMCNT0();
  BAR();

  for (int t = 0; t < NT; t += 2) {
    G2_TILE(0, t)
    G2_TILE(1, t + 1)
  }

  const int er = (lane >> 4) << 2;
  const int ec = lane & 15;
#pragma unroll
  for (int mi = 0; mi < 8; ++mi)
#pragma unroll
    for (int n = 0; n < 4; ++n)
#pragma unroll
      for (int r = 0; r < 4; ++r) {
        size_t row = (size_t)(bm + wr * 128 + mi * 16 + er + r);
        size_t col = (size_t)(bn + wc * 64 + n * 16 + ec);
        C[row * N + col] = acc[mi][n][r];
      }
}

// ======================= GEMM1: dual-B + silu fuse =========================
// tile 256x128, BK=64, 8 waves (4M x 2N), per-wave 64x64, dual accum.
// LDS (ushorts): A [0,32768), B1 [32768,49152), B3 [49152,65536).
// Compiler-free body (same discipline as gemm2).
#define G1_TILE(bi, tt)                                                       \
  {                                                                           \
    if ((tt) + 1 < NT) {                                                      \
      unsigned short* dA = L + (((bi) ^ 1) * 16384) + wid * 512;              \
      unsigned short* dB1 = L + 32768 + (((bi) ^ 1) * 8192) + wid * 512;      \
      unsigned short* dB3 = L + 49152 + (((bi) ^ 1) * 8192) + wid * 512;      \
      _Pragma("unroll") for (int i = 0; i < 4; ++i)                           \
          GLOAD_LDS16(pA + i * s64, dA + i * 4096);                           \
      _Pragma("unroll") for (int i = 0; i < 2; ++i) {                         \
        GLOAD_LDS16(pB1 + i * s64, dB1 + i * 4096);                           \
        GLOAD_LDS16(pB3 + i * s64, dB3 + i * 4096);                           \
      }                                                                       \
    }                                                                         \
    SB0();                                                                    \
    _Pragma("unroll") for (int m = 0; m < 4; ++m) {                           \
      ra[m][0] = *(const bf16x8*)(Lb + ((bi)*32768 + m * 2048) + rA0);        \
      ra[m][1] = *(const bf16x8*)(Lb + ((bi)*32768 + m * 2048) + rA1);        \
    }                                                                         \
    _Pragma("unroll") for (int n = 0; n < 4; ++n) {                           \
      rb1[n][0] = *(const bf16x8*)(Lb + (65536 + (bi)*16384 + n * 2048) + rB0);\
      rb1[n][1] = *(const bf16x8*)(Lb + (65536 + (bi)*16384 + n * 2048) + rB1);\
      rb3[n][0] = *(const bf16x8*)(Lb + (98304 + (bi)*16384 + n * 2048) + rB0);\
      rb3[n][1] = *(const bf16x8*)(Lb + (98304 + (bi)*16384 + n * 2048) + rB1);\
    }                                                                         \
    _Pragma("unroll") for (int m = 0; m < 4; ++m)                             \
        _Pragma("unroll") for (int n = 0; n < 4; ++n)                         \
            _Pragma("unroll") for (int ks = 0; ks < 2; ++ks) {                \
      accG[m][n] = MFMA_BF16(ra[m][ks], rb1[n][ks], accG[m][n], 0, 0, 0);     \
      accL[m][n] = MFMA_BF16(ra[m][ks], rb3[n][ks], accL[m][n], 0, 0, 0);     \
    }                                                                         \
    LGKM0();                                                                  \
    VMCNT0();                                                                 \
    BAR();                                                                    \
    pA += 128;                                                                \
    pB1 += 128;                                                               \
    pB3 += 128;                                                               \
  }

__launch_bounds__(512, 2)
__global__ void gemm1_pipe(const unsigned short* __restrict__ A,
                           const unsigned short* __restrict__ B1p,
                           const unsigned short* __restrict__ B3p,
                           unsigned short* __restrict__ Hout, int M, int N,
                           int K) {
  __shared__ __align__(16) unsigned short L[65536];
  const int tid = threadIdx.x, lane = tid & 63, wid = tid >> 6;
  const int wr = wid >> 1, wc = wid & 1;
  const int nby = M >> 8;  // 32
  const int cpx = (int)gridDim.x >> 3;
  const int swz = ((int)blockIdx.x & 7) * cpx + ((int)blockIdx.x >> 3);
  const int bm = (swz % nby) << 8;
  const int bn = (swz / nby) << 7;
  const int NT = K >> 6;

  const int lp0 = (lane & 15) * 128 + (((lane >> 4) << 4) ^ ((lane & 7) << 4));
  const int lp1 =
      (lane & 15) * 128 + ((64 | ((lane >> 4) << 4)) ^ ((lane & 7) << 4));
  const int rA0 = wr * 8192 + lp0, rA1 = wr * 8192 + lp1;
  const int rB0 = wc * 8192 + lp0, rB1 = wc * 8192 + lp1;

  const int swzc = ((lane & 7) ^ (lane >> 3)) << 4;
  const char* pA = (const char*)A +
                   ((size_t)(bm + (wid << 3) + (lane >> 3)) * K) * 2 + swzc;
  const char* pB1 = (const char*)B1p +
                    ((size_t)(bn + (wid << 3) + (lane >> 3)) * K) * 2 + swzc;
  const char* pB3 = (const char*)B3p +
                    ((size_t)(bn + (wid << 3) + (lane >> 3)) * K) * 2 + swzc;
  const size_t s64 = (size_t)K * 128;
  const char* Lb = (const char*)L;

  {  // prologue
    unsigned short* dA = L + wid * 512;
    unsigned short* dB1 = L + 32768 + wid * 512;
    unsigned short* dB3 = L + 49152 + wid * 512;
#pragma unroll
    for (int i = 0; i < 4; ++i) GLOAD_LDS16(pA + i * s64, dA + i * 4096);
#pragma unroll
    for (int i = 0; i < 2; ++i) {
      GLOAD_LDS16(pB1 + i * s64, dB1 + i * 4096);
      GLOAD_LDS16(pB3 + i * s64, dB3 + i * 4096);
    }
  }
  pA += 128;
  pB1 += 128;
  pB3 += 128;

  f32x4 accG[4][4], accL[4][4];
#pragma unroll
  for (int m = 0; m < 4; ++m)
#pragma unroll
    for (int n = 0; n < 4; ++n) {
      accG[m][n] = (f32x4)0.0f;
      accL[m][n] = (f32x4)0.0f;
    }
  bf16x8 ra[4][2], rb1[4][2], rb3[4][2];

  VMCNT0();
  BAR();

  for (int t = 0; t < NT; t += 2) {
    G1_TILE(0, t)
    G1_TILE(1, t + 1)
  }

  const int er = (lane >> 4) << 2;
  const int ec = lane & 15;
#pragma unroll
  for (int m = 0; m < 4; ++m)
#pragma unroll
    for (int n = 0; n < 4; ++n)
#pragma unroll
      for (int r = 0; r < 4; ++r) {
        float g = accG[m][n][r];
        float li = accL[m][n][r];
        float h = (g / (1.0f + __expf(-g))) * li;
        size_t row = (size_t)(bm + wr * 64 + m * 16 + er + r);
        size_t col = (size_t)(bn + wc * 64 + n * 16 + ec);
        Hout[row * N + col] = f32_to_bf16(h);
      }
}

extern "C" void kernel_launch(void* const* d_in, const int* in_sizes, int n_in,
                              void* d_out, int out_size, void* d_ws,
                              size_t ws_size, hipStream_t stream) {
  const float* x = (const float*)d_in[0];   // (4,2048,2048)
  const float* W1 = (const float*)d_in[1];  // (8192,2048)
  const float* W2 = (const float*)d_in[2];  // (2048,8192)
  const float* W3 = (const float*)d_in[3];  // (8192,2048)
  float* out = (float*)d_out;

  const int M = 8192, D = 2048, H = 8192;
  const size_t NE = (size_t)16777216;

  unsigned short* xb = (unsigned short*)d_ws;
  unsigned short* w1b = xb + NE;
  unsigned short* w3b = w1b + NE;
  unsigned short* w2f = w3b + NE;
  unsigned short* hid = w2f + NE;  // M x H bf16

  conv3_f32_bf16<<<3072, 256, 0, stream>>>(x, xb, W1, w1b, W3, w3b,
                                           (int)(NE / 4));
  fwht_rows_bf16<<<2048, 256, 0, stream>>>(W2, w2f);

  gemm1_pipe<<<(M / 256) * (H / 128), 512, 0, stream>>>(xb, w1b, w3b, hid, M,
                                                        H, D);
  gemm2_pipe<<<(M / 256) * (D / 256), 512, 0, stream>>>(hid, w2f, out, M, D,
                                                        H);
}